// Round 8
// baseline (381.174 us; speedup 1.0000x reference)
//
#include <hip/hip_runtime.h>
#include <stdint.h>
#include <stddef.h>

// ISNNet: x[:,0]=x0; x[:,t] = x[:,t-1] @ eW.T + I[:,t-1] @ W_inv_eW.T
// B=64, T=2048, D=256.  3-term compensated bf16 MFMA throughout.
// Round 8: revert k_power (device spin barrier cost ~13us/barrier) back to
// 7x k_mm256 launches; 3-accumulator ILP in k_u/k_scan inner loops
// (independent MFMA chains instead of one 24-deep dependent chain).

#define BATCH 64
#define TLEN 2048
#define DDIM 256
#define CHUNK 32
#define NCHUNK 64

typedef __attribute__((ext_vector_type(8))) short short8;
typedef __attribute__((ext_vector_type(4))) short short4_t;
typedef __attribute__((ext_vector_type(4))) float f32x4;

#define MFMA16(a, b, c) __builtin_amdgcn_mfma_f32_16x16x32_bf16((a), (b), (c), 0, 0, 0)
#define PIN8(x) asm volatile("" : "+v"(x))

__device__ __forceinline__ uint16_t f2bf(float f) {
  union { float f; uint32_t u; } v; v.f = f;
  return (uint16_t)((v.u + 0x7fffu + ((v.u >> 16) & 1u)) >> 16);  // RNE
}
__device__ __forceinline__ float bf2f(uint16_t h) {
  union { uint32_t u; float f; } v; v.u = ((uint32_t)h) << 16;
  return v.f;
}

__device__ __forceinline__ void split8(const float* fv, short8& hi, short8& lo) {
#pragma unroll
  for (int j = 0; j < 8; ++j) {
    uint16_t hb = f2bf(fv[j]);
    hi[j] = (short)hb;
    lo[j] = (short)f2bf(fv[j] - bf2f(hb));
  }
}

// rows 0..15 spread over 16 distinct 16B slots within 2 x 128B lines
__device__ __forceinline__ uint32_t swz(int row) {
  return ((uint32_t)((row & 7) << 4)) ^ ((uint32_t)(((row >> 3) & 1) << 7));
}

// raw barrier: waits LDS ops but NOT outstanding global loads
__device__ __forceinline__ void wg_barrier() {
  __builtin_amdgcn_sched_barrier(0);
  asm volatile("s_waitcnt lgkmcnt(0)" ::: "memory");
  __builtin_amdgcn_s_barrier();
  asm volatile("" ::: "memory");
  __builtin_amdgcn_sched_barrier(0);
}

// ---------------- workspace layout (bytes) ----------------
#define WS_A_HI   (0)
#define WS_A_LO   (128 * 1024)
#define WS_WB_HI  (256 * 1024)
#define WS_WB_LO  (384 * 1024)
#define WS_M1F    (512 * 1024)   // f32 [256][256]
#define WS_M1_HI  (768 * 1024)
#define WS_M1_LO  (896 * 1024)
#define WS_M2F    (1024 * 1024)
#define WS_M2_HI  (1280 * 1024)
#define WS_M2_LO  (1408 * 1024)
#define WS_M3F    (1536 * 1024)
#define WS_M3_HI  (1792 * 1024)
#define WS_M3_LO  (1920 * 1024)
#define WS_ATF    (2048 * 1024)  // f32 eW^T (A1 row-major), 256KB
#define WS_S      (2560 * 1024)  // f32 [64][64][256] = 4MB
#define WS_Y      (6656 * 1024)  // f32 [64][64][256] = 4MB

// ---------------- k_split ----------------
__global__ void k_split(const float* __restrict__ eW, const float* __restrict__ Wi,
                        uint16_t* __restrict__ Ah, uint16_t* __restrict__ Al,
                        uint16_t* __restrict__ Wh, uint16_t* __restrict__ Wl,
                        float* __restrict__ AtF) {
  int idx = blockIdx.x * blockDim.x + threadIdx.x;
  if (idx < 65536) {
    float v = eW[idx];
    uint16_t h = f2bf(v);
    Ah[idx] = h;
    Al[idx] = f2bf(v - bf2f(h));
    AtF[(idx & 255) * 256 + (idx >> 8)] = v;  // AtF[k][n] = eW[n][k]
  } else if (idx < 131072) {
    int i = idx - 65536;
    float v = Wi[i];
    uint16_t h = f2bf(v);
    Wh[i] = h;
    Wl[i] = f2bf(v - bf2f(h));
  }
}

// ---------------- k_u: u = I @ Wb, stored into d_out at time t+1 ----------------
// 16-wave WGs, 16 cols/wave; 256 WGs x 32 tiles; LDS dbuf; 3-acc ILP.
__global__ __launch_bounds__(1024, 1) void k_u(const float* __restrict__ I,
                                               const uint16_t* __restrict__ Wh,
                                               const uint16_t* __restrict__ Wl,
                                               float* __restrict__ out) {
  const int tid = threadIdx.x;
  const int w = tid >> 6, l = tid & 63, l15 = l & 15, quad = l >> 4;
  const int ns = w * 16;  // 16 cols per wave
  __shared__ __align__(16) uint16_t sIh[2][4096];  // 16 x 256 bf16, XOR-swizzled
  __shared__ __align__(16) uint16_t sIl[2][4096];

  // Wb column-slice fragments (64 VGPR/wave, pinned)
  short8 bh[8], bl[8];
#pragma unroll
  for (int ks = 0; ks < 8; ++ks) {
    const int off = (ns + l15) * 256 + ks * 32 + quad * 8;
    bh[ks] = *reinterpret_cast<const short8*>(Wh + off);
    bl[ks] = *reinterpret_cast<const short8*>(Wl + off);
    PIN8(bh[ks]);
    PIN8(bl[ks]);
  }

  const int srow = tid >> 6;        // 0..15 (staging row = wave id)
  const int sc0 = (tid & 63) * 4;   // 0..252 (staging col base)
  const uint32_t wbyte = ((uint32_t)(srow * 512 + sc0 * 2)) ^ swz(srow);

  f32x4 ra, rb, rc, rd;
  auto loadI = [&](int tl, f32x4& dst) {
    const int b = tl >> 7, tt = tl & 127;
    dst = *reinterpret_cast<const f32x4*>(I + ((size_t)b * TLEN + tt * 16 + srow) * DDIM + sc0);
  };

  auto do_tile = [&](int tl, f32x4& cur, f32x4& pf, int q, bool pre) {
    if (pre) loadI(tl + 512, pf);    // prefetch tile tl+2 (stride 256)
    short4_t hi4, lo4;
#pragma unroll
    for (int j = 0; j < 4; ++j) {
      uint16_t hb = f2bf(cur[j]);
      hi4[j] = (short)hb;
      lo4[j] = (short)f2bf(cur[j] - bf2f(hb));
    }
    *reinterpret_cast<short4_t*>(reinterpret_cast<char*>(sIh[q]) + wbyte) = hi4;
    *reinterpret_cast<short4_t*>(reinterpret_cast<char*>(sIl[q]) + wbyte) = lo4;
    wg_barrier();                    // writes of buf q visible; buf q^1 free
    const int b = tl >> 7, tt = tl & 127;
    f32x4 aH = {0.f, 0.f, 0.f, 0.f}, aL = {0.f, 0.f, 0.f, 0.f}, aM = {0.f, 0.f, 0.f, 0.f};
    __builtin_amdgcn_s_setprio(1);
#pragma unroll
    for (int ks = 0; ks < 8; ++ks) {
      uint32_t rbyte = ((uint32_t)(l15 * 512 + ks * 64 + quad * 16)) ^ swz(l15);
      short8 ih = *reinterpret_cast<const short8*>((const char*)sIh[q] + rbyte);
      short8 il = *reinterpret_cast<const short8*>((const char*)sIl[q] + rbyte);
      aH = MFMA16(ih, bh[ks], aH);
      aL = MFMA16(il, bh[ks], aL);
      aM = MFMA16(ih, bl[ks], aM);
    }
    __builtin_amdgcn_s_setprio(0);
#pragma unroll
    for (int r = 0; r < 4; ++r) {
      int trow = tt * 16 + quad * 4 + r;
      if (trow <= TLEN - 2) {  // u_t lives at location t+1; t <= 2046
        out[((size_t)b * TLEN + trow + 1) * DDIM + ns + l15] =
            aH[r] + (aL[r] + aM[r]);
      }
    }
  };

  const int tl0 = blockIdx.x;  // 32 tiles: tl0 + k*256
  loadI(tl0, ra);
  loadI(tl0 + 256, rb);
#pragma unroll 1
  for (int it = 0; it < 32; it += 4) {
    do_tile(tl0 + (it + 0) * 256, ra, rc, 0, it + 2 < 32);
    do_tile(tl0 + (it + 1) * 256, rb, rd, 1, it + 3 < 32);
    do_tile(tl0 + (it + 2) * 256, rc, ra, 0, it + 4 < 32);
    do_tile(tl0 + (it + 3) * 256, rd, rb, 1, it + 5 < 32);
  }
}

// ---------------- k_scan: in-chunk recurrence (CHUNK=32), 16-wave WGs ----------------
__global__ __launch_bounds__(1024) void k_scan(const int pass,
                                               const uint16_t* __restrict__ Ah,
                                               const uint16_t* __restrict__ Al,
                                               float* __restrict__ xu,  // d_out: u in (shifted), x out
                                               const float* __restrict__ Y,
                                               float* __restrict__ S) {
  const int tid = threadIdx.x;
  const int w = tid >> 6, l = tid & 63, l15 = l & 15, quad = l >> 4;
  const int ns = w * 16;  // 16 cols per wave
  const int c = blockIdx.x >> 2;
  const int rg = blockIdx.x & 3;
  __shared__ __align__(16) uint16_t sh[2][4096];
  __shared__ __align__(16) uint16_t sl[2][4096];

  const int t0 = c * CHUNK;
  const int nsteps = (t0 + CHUNK <= TLEN - 1) ? CHUNK : (TLEN - 1 - t0);

  float u0[4], u1[4], u2[4], u3[4], fin[4];
#pragma unroll
  for (int j = 0; j < 4; ++j) { u0[j] = 0.f; u1[j] = 0.f; u2[j] = 0.f; u3[j] = 0.f; fin[j] = 0.f; }

  auto issue_u = [&](int i, float (&dst)[4]) {
    if (i > nsteps) return;
#pragma unroll
    for (int r = 0; r < 4; ++r) {
      int b = rg * 16 + quad * 4 + r;
      dst[r] = xu[((size_t)b * TLEN + t0 + i) * DDIM + ns + l15];
    }
  };
  issue_u(1, u0);
  issue_u(2, u1);
  issue_u(3, u2);
  issue_u(4, u3);

  // A fragments: per-wave 16-col slice (64 VGPR, pinned)
  short8 fAh[8], fAl[8];
#pragma unroll
  for (int ks = 0; ks < 8; ++ks) {
    const int off = (ns + l15) * 256 + ks * 32 + quad * 8;
    fAh[ks] = *reinterpret_cast<const short8*>(Ah + off);
    fAl[ks] = *reinterpret_cast<const short8*>(Al + off);
    PIN8(fAh[ks]);
    PIN8(fAl[ks]);
  }

  // init state (buf 0)
  for (int i = tid; i < 4096; i += 1024) {
    int row = i >> 8, k = i & 255;
    float v;
    if (pass == 1)
      v = 0.0f;
    else {
      v = Y[((size_t)c * 64 + rg * 16 + row) * DDIM + k];
      if (c == 0) xu[((size_t)(rg * 16 + row) * TLEN) * DDIM + k] = v;  // x[:,0,:] = x0
    }
    uint16_t hb = f2bf(v);
    uint16_t lb = f2bf(v - bf2f(hb));
    uint32_t byte = ((uint32_t)(row * 512 + k * 2)) ^ swz(row);
    *(uint16_t*)((char*)sh[0] + byte) = hb;
    *(uint16_t*)((char*)sl[0] + byte) = lb;
  }
  wg_barrier();  // no vmcnt drain: u prefetches stay in flight

  int p = 0;
  auto step = [&](int i, float (&ucur)[4]) {
    f32x4 aH = {0.f, 0.f, 0.f, 0.f}, aL = {0.f, 0.f, 0.f, 0.f}, aM = {0.f, 0.f, 0.f, 0.f};
    __builtin_amdgcn_s_setprio(1);
#pragma unroll
    for (int ks = 0; ks < 8; ++ks) {
      uint32_t byte = ((uint32_t)(l15 * 512 + ks * 64 + quad * 16)) ^ swz(l15);
      short8 xh = *reinterpret_cast<const short8*>((const char*)sh[p] + byte);
      short8 xl = *reinterpret_cast<const short8*>((const char*)sl[p] + byte);
      aH = MFMA16(xh, fAh[ks], aH);
      aL = MFMA16(xl, fAh[ks], aL);
      aM = MFMA16(xh, fAl[ks], aM);
    }
    __builtin_amdgcn_s_setprio(0);
#pragma unroll
    for (int r = 0; r < 4; ++r) fin[r] = (aH[r] + (aL[r] + aM[r])) + ucur[r];
    issue_u(i + 4, ucur);  // refill this buffer for step i+4
    if (pass == 2) {
#pragma unroll
      for (int r = 0; r < 4; ++r) {
        int b = rg * 16 + quad * 4 + r;
        xu[((size_t)b * TLEN + t0 + i) * DDIM + ns + l15] = fin[r];
      }
    }
    if (i < nsteps) {
#pragma unroll
      for (int r = 0; r < 4; ++r) {
        int row = quad * 4 + r, col = ns + l15;
        float v = fin[r];
        uint16_t hb = f2bf(v);
        uint16_t lb = f2bf(v - bf2f(hb));
        uint32_t byte = ((uint32_t)(row * 512 + col * 2)) ^ swz(row);
        *(uint16_t*)((char*)sh[p ^ 1] + byte) = hb;
        *(uint16_t*)((char*)sl[p ^ 1] + byte) = lb;
      }
      wg_barrier();
      p ^= 1;
    }
  };

  int i = 1;
  for (; i + 3 <= nsteps; i += 4) {
    step(i, u0);
    step(i + 1, u1);
    step(i + 2, u2);
    step(i + 3, u3);
  }
  if (i <= nsteps) { step(i, u0); ++i; }
  if (i <= nsteps) { step(i, u1); ++i; }
  if (i <= nsteps) { step(i, u2); ++i; }

  if (pass == 1) {
#pragma unroll
    for (int r = 0; r < 4; ++r) {
      int row = quad * 4 + r, col = ns + l15;
      S[((size_t)c * 64 + rg * 16 + row) * DDIM + col] = fin[r];
    }
  }
}

// ---------------- k_mm256: OUT = Af @ B, 16 WGs ----------------
__global__ __launch_bounds__(512) void k_mm256(const float* __restrict__ Af,
                                               const uint16_t* __restrict__ Bh,
                                               const uint16_t* __restrict__ Bl,
                                               float* __restrict__ Of,
                                               uint16_t* __restrict__ Oh,
                                               uint16_t* __restrict__ Ol) {
  const int mf = blockIdx.x;  // 0..15
  const int tid = threadIdx.x;
  const int w = tid >> 6, l = tid & 63, l15 = l & 15, quad = l >> 4;
  const int ns = w * 32;
  f32x4 acc[2];
  acc[0] = {0.f, 0.f, 0.f, 0.f};
  acc[1] = {0.f, 0.f, 0.f, 0.f};

#pragma unroll
  for (int ks = 0; ks < 8; ++ks) {
    const float* ap = Af + (size_t)(mf * 16 + l15) * 256 + ks * 32 + quad * 8;
    f32x4 f0 = *reinterpret_cast<const f32x4*>(ap);
    f32x4 f1 = *reinterpret_cast<const f32x4*>(ap + 4);
    float fv[8] = {f0[0], f0[1], f0[2], f0[3], f1[0], f1[1], f1[2], f1[3]};
    short8 ah, al8;
    split8(fv, ah, al8);
#pragma unroll
    for (int nf = 0; nf < 2; ++nf) {
      const int off = (ns + nf * 16 + l15) * 256 + ks * 32 + quad * 8;
      short8 bhf = *reinterpret_cast<const short8*>(Bh + off);
      short8 blf = *reinterpret_cast<const short8*>(Bl + off);
      acc[nf] = MFMA16(ah, bhf, acc[nf]);
      acc[nf] = MFMA16(al8, bhf, acc[nf]);
      acc[nf] = MFMA16(ah, blf, acc[nf]);
    }
  }
#pragma unroll
  for (int nf = 0; nf < 2; ++nf)
#pragma unroll
    for (int r = 0; r < 4; ++r) {
      int row = mf * 16 + quad * 4 + r;
      int col = ns + nf * 16 + l15;
      float v = acc[nf][r];
      Of[(size_t)row * 256 + col] = v;
      uint16_t hb = f2bf(v);
      Oh[(size_t)col * 256 + row] = hb;
      Ol[(size_t)col * 256 + row] = f2bf(v - bf2f(hb));
    }
}

// ---------------- k_bnd: boundary states, J=3 ----------------
// Y_c = T_c + T_{c-1}@M1 + T_{c-2}@M2 + T_{c-3}@M3; T_0=x0, T_k=S_{k-1}.
__global__ __launch_bounds__(512) void k_bnd(const float* __restrict__ x0,
                                             const float* __restrict__ S,
                                             const uint16_t* __restrict__ M1h, const uint16_t* __restrict__ M1l,
                                             const uint16_t* __restrict__ M2h, const uint16_t* __restrict__ M2l,
                                             const uint16_t* __restrict__ M3h, const uint16_t* __restrict__ M3l,
                                             float* __restrict__ Y) {
  const int c = blockIdx.x;
  const int tid = threadIdx.x;
  const int w = tid >> 6, l = tid & 63, l15 = l & 15, quad = l >> 4;
  const int ns = w * 32;
  f32x4 acc[4][2];
  const float* Tc = (c == 0) ? x0 : (S + (size_t)(c - 1) * 64 * 256);
#pragma unroll
  for (int mf = 0; mf < 4; ++mf)
#pragma unroll
    for (int nf = 0; nf < 2; ++nf)
#pragma unroll
      for (int r = 0; r < 4; ++r)
        acc[mf][nf][r] = Tc[(size_t)(mf * 16 + quad * 4 + r) * 256 + ns + nf * 16 + l15];

  for (int j = 1; j <= 3; ++j) {
    int k = c - j;
    if (k < 0) break;
    const float* Tp = (k == 0) ? x0 : (S + (size_t)(k - 1) * 64 * 256);
    const uint16_t* Bh = (j == 1) ? M1h : (j == 2) ? M2h : M3h;
    const uint16_t* Bl = (j == 1) ? M1l : (j == 2) ? M2l : M3l;
#pragma unroll
    for (int mf = 0; mf < 4; ++mf) {
#pragma unroll
      for (int ks = 0; ks < 8; ++ks) {
        const float* ap = Tp + (size_t)(mf * 16 + l15) * 256 + ks * 32 + quad * 8;
        f32x4 f0 = *reinterpret_cast<const f32x4*>(ap);
        f32x4 f1 = *reinterpret_cast<const f32x4*>(ap + 4);
        float fv[8] = {f0[0], f0[1], f0[2], f0[3], f1[0], f1[1], f1[2], f1[3]};
        short8 ah, al8;
        split8(fv, ah, al8);
#pragma unroll
        for (int nf = 0; nf < 2; ++nf) {
          const int off = (ns + nf * 16 + l15) * 256 + ks * 32 + quad * 8;
          short8 bhf = *reinterpret_cast<const short8*>(Bh + off);
          short8 blf = *reinterpret_cast<const short8*>(Bl + off);
          acc[mf][nf] = MFMA16(ah, bhf, acc[mf][nf]);
          acc[mf][nf] = MFMA16(al8, bhf, acc[mf][nf]);
          acc[mf][nf] = MFMA16(ah, blf, acc[mf][nf]);
        }
      }
    }
  }
#pragma unroll
  for (int mf = 0; mf < 4; ++mf)
#pragma unroll
    for (int nf = 0; nf < 2; ++nf)
#pragma unroll
      for (int r = 0; r < 4; ++r)
        Y[(size_t)c * 64 * 256 + (size_t)(mf * 16 + quad * 4 + r) * 256 + ns + nf * 16 + l15] =
            acc[mf][nf][r];
}

// ---------------- launch ----------------
extern "C" void kernel_launch(void* const* d_in, const int* in_sizes, int n_in,
                              void* d_out, int out_size, void* d_ws, size_t ws_size,
                              hipStream_t stream) {
  (void)in_sizes; (void)n_in; (void)out_size; (void)ws_size;
  const float* x0 = (const float*)d_in[0];
  const float* I  = (const float*)d_in[1];
  const float* eW = (const float*)d_in[2];
  const float* Wi = (const float*)d_in[3];
  float* out = (float*)d_out;
  char* ws = (char*)d_ws;

  uint16_t* Ah  = (uint16_t*)(ws + WS_A_HI);
  uint16_t* Al  = (uint16_t*)(ws + WS_A_LO);
  uint16_t* Wh  = (uint16_t*)(ws + WS_WB_HI);
  uint16_t* Wl  = (uint16_t*)(ws + WS_WB_LO);
  float*    M1f = (float*)(ws + WS_M1F);
  uint16_t* M1h = (uint16_t*)(ws + WS_M1_HI);
  uint16_t* M1l = (uint16_t*)(ws + WS_M1_LO);
  float*    M2f = (float*)(ws + WS_M2F);
  uint16_t* M2h = (uint16_t*)(ws + WS_M2_HI);
  uint16_t* M2l = (uint16_t*)(ws + WS_M2_LO);
  float*    M3f = (float*)(ws + WS_M3F);
  uint16_t* M3h = (uint16_t*)(ws + WS_M3_HI);
  uint16_t* M3l = (uint16_t*)(ws + WS_M3_LO);
  float*    AtF = (float*)(ws + WS_ATF);
  float*    S   = (float*)(ws + WS_S);
  float*    Y   = (float*)(ws + WS_Y);

  k_split<<<512, 256, 0, stream>>>(eW, Wi, Ah, Al, Wh, Wl, AtF);
  k_u<<<256, 1024, 0, stream>>>(I, Wh, Wl, out);
  // M-power chain: A^2 -> A^4 -> A^8 -> A^16 -> A^32(M1) -> A^64(M2) -> A^96(M3)
  k_mm256<<<16, 512, 0, stream>>>(AtF, Ah, Al, M2f, M2h, M2l);    // A^2
  k_mm256<<<16, 512, 0, stream>>>(M2f, M2h, M2l, M3f, M3h, M3l);  // A^4
  k_mm256<<<16, 512, 0, stream>>>(M3f, M3h, M3l, M2f, M2h, M2l);  // A^8
  k_mm256<<<16, 512, 0, stream>>>(M2f, M2h, M2l, M3f, M3h, M3l);  // A^16
  k_mm256<<<16, 512, 0, stream>>>(M3f, M3h, M3l, M1f, M1h, M1l);  // A^32
  k_mm256<<<16, 512, 0, stream>>>(M1f, M1h, M1l, M2f, M2h, M2l);  // A^64
  k_mm256<<<16, 512, 0, stream>>>(M2f, M1h, M1l, M3f, M3h, M3l);  // A^96
  k_scan<<<256, 1024, 0, stream>>>(1, Ah, Al, out, Y, S);
  k_bnd<<<64, 512, 0, stream>>>(x0, S, M1h, M1l, M2h, M2l, M3h, M3l, Y);
  k_scan<<<256, 1024, 0, stream>>>(2, Ah, Al, out, Y, S);
}

// Round 9
// 297.381 us; speedup vs baseline: 1.2818x; 1.2818x over previous
//
#include <hip/hip_runtime.h>
#include <stdint.h>
#include <stddef.h>

// ISNNet: x[:,0]=x0; x[:,t] = x[:,t-1] @ eW.T + I[:,t-1] @ W_inv_eW.T
// B=64, T=2048, D=256.  3-term compensated bf16 MFMA throughout.
// Round 9: revert 3-acc ILP (r8 regression — XDL forwards same-acc chains);
// kill k_split (consumers self-split from f32 weights); J=2 boundary
// (chain 7->6 mms). 12 -> 10 dispatches (~6us/dispatch gap measured).

#define BATCH 64
#define TLEN 2048
#define DDIM 256
#define CHUNK 32
#define NCHUNK 64

typedef __attribute__((ext_vector_type(8))) short short8;
typedef __attribute__((ext_vector_type(4))) short short4_t;
typedef __attribute__((ext_vector_type(4))) float f32x4;

#define MFMA16(a, b, c) __builtin_amdgcn_mfma_f32_16x16x32_bf16((a), (b), (c), 0, 0, 0)
#define PIN8(x) asm volatile("" : "+v"(x))

__device__ __forceinline__ uint16_t f2bf(float f) {
  union { float f; uint32_t u; } v; v.f = f;
  return (uint16_t)((v.u + 0x7fffu + ((v.u >> 16) & 1u)) >> 16);  // RNE
}
__device__ __forceinline__ float bf2f(uint16_t h) {
  union { uint32_t u; float f; } v; v.u = ((uint32_t)h) << 16;
  return v.f;
}

__device__ __forceinline__ void split8(const float* fv, short8& hi, short8& lo) {
#pragma unroll
  for (int j = 0; j < 8; ++j) {
    uint16_t hb = f2bf(fv[j]);
    hi[j] = (short)hb;
    lo[j] = (short)f2bf(fv[j] - bf2f(hb));
  }
}

// rows 0..15 spread over 16 distinct 16B slots within 2 x 128B lines
__device__ __forceinline__ uint32_t swz(int row) {
  return ((uint32_t)((row & 7) << 4)) ^ ((uint32_t)(((row >> 3) & 1) << 7));
}

// raw barrier: waits LDS ops but NOT outstanding global loads
__device__ __forceinline__ void wg_barrier() {
  __builtin_amdgcn_sched_barrier(0);
  asm volatile("s_waitcnt lgkmcnt(0)" ::: "memory");
  __builtin_amdgcn_s_barrier();
  asm volatile("" ::: "memory");
  __builtin_amdgcn_sched_barrier(0);
}

// ---------------- workspace layout (bytes) ----------------
#define WS_M1F    (0)            // f32 [256][256]
#define WS_M1_HI  (256 * 1024)
#define WS_M1_LO  (384 * 1024)
#define WS_M2F    (512 * 1024)
#define WS_M2_HI  (768 * 1024)
#define WS_M2_LO  (896 * 1024)
#define WS_M3F    (1024 * 1024)
#define WS_M3_HI  (1280 * 1024)
#define WS_M3_LO  (1408 * 1024)
#define WS_S      (2560 * 1024)  // f32 [64][64][256] = 4MB
#define WS_Y      (6656 * 1024)  // f32 [64][64][256] = 4MB

// ---------------- k_u: u = I @ Wi^T, stored into d_out at time t+1 ----------------
// 16-wave WGs, 16 cols/wave; 256 WGs x 32 tiles; LDS dbuf; single-acc chains;
// Wb fragments self-split from f32 Wi (no k_split dependency).
__global__ __launch_bounds__(1024, 1) void k_u(const float* __restrict__ I,
                                               const float* __restrict__ Wi,
                                               float* __restrict__ out) {
  const int tid = threadIdx.x;
  const int w = tid >> 6, l = tid & 63, l15 = l & 15, quad = l >> 4;
  const int ns = w * 16;  // 16 cols per wave
  __shared__ __align__(16) uint16_t sIh[2][4096];  // 16 x 256 bf16, XOR-swizzled
  __shared__ __align__(16) uint16_t sIl[2][4096];

  // Wb column-slice fragments: split from f32 Wi (row n = output col), pinned
  short8 bh[8], bl[8];
#pragma unroll
  for (int ks = 0; ks < 8; ++ks) {
    const float* wp = Wi + (size_t)(ns + l15) * 256 + ks * 32 + quad * 8;
    f32x4 f0 = *reinterpret_cast<const f32x4*>(wp);
    f32x4 f1 = *reinterpret_cast<const f32x4*>(wp + 4);
    float fv[8] = {f0[0], f0[1], f0[2], f0[3], f1[0], f1[1], f1[2], f1[3]};
    split8(fv, bh[ks], bl[ks]);
    PIN8(bh[ks]);
    PIN8(bl[ks]);
  }

  const int srow = tid >> 6;        // 0..15 (staging row = wave id)
  const int sc0 = (tid & 63) * 4;   // 0..252 (staging col base)
  const uint32_t wbyte = ((uint32_t)(srow * 512 + sc0 * 2)) ^ swz(srow);

  f32x4 ra, rb, rc, rd;
  auto loadI = [&](int tl, f32x4& dst) {
    const int b = tl >> 7, tt = tl & 127;
    dst = *reinterpret_cast<const f32x4*>(I + ((size_t)b * TLEN + tt * 16 + srow) * DDIM + sc0);
  };

  auto do_tile = [&](int tl, f32x4& cur, f32x4& pf, int q, bool pre) {
    if (pre) loadI(tl + 512, pf);    // prefetch tile tl+2 (stride 256)
    short4_t hi4, lo4;
#pragma unroll
    for (int j = 0; j < 4; ++j) {
      uint16_t hb = f2bf(cur[j]);
      hi4[j] = (short)hb;
      lo4[j] = (short)f2bf(cur[j] - bf2f(hb));
    }
    *reinterpret_cast<short4_t*>(reinterpret_cast<char*>(sIh[q]) + wbyte) = hi4;
    *reinterpret_cast<short4_t*>(reinterpret_cast<char*>(sIl[q]) + wbyte) = lo4;
    wg_barrier();                    // writes of buf q visible; buf q^1 free
    const int b = tl >> 7, tt = tl & 127;
    f32x4 acc = {0.f, 0.f, 0.f, 0.f};
    __builtin_amdgcn_s_setprio(1);
#pragma unroll
    for (int ks = 0; ks < 8; ++ks) {
      uint32_t rbyte = ((uint32_t)(l15 * 512 + ks * 64 + quad * 16)) ^ swz(l15);
      short8 ih = *reinterpret_cast<const short8*>((const char*)sIh[q] + rbyte);
      short8 il = *reinterpret_cast<const short8*>((const char*)sIl[q] + rbyte);
      acc = MFMA16(ih, bh[ks], acc);
      acc = MFMA16(il, bh[ks], acc);
      acc = MFMA16(ih, bl[ks], acc);
    }
    __builtin_amdgcn_s_setprio(0);
#pragma unroll
    for (int r = 0; r < 4; ++r) {
      int trow = tt * 16 + quad * 4 + r;
      if (trow <= TLEN - 2) {  // u_t lives at location t+1; t <= 2046
        out[((size_t)b * TLEN + trow + 1) * DDIM + ns + l15] = acc[r];
      }
    }
  };

  const int tl0 = blockIdx.x;  // 32 tiles: tl0 + k*256
  loadI(tl0, ra);
  loadI(tl0 + 256, rb);
#pragma unroll 1
  for (int it = 0; it < 32; it += 4) {
    do_tile(tl0 + (it + 0) * 256, ra, rc, 0, it + 2 < 32);
    do_tile(tl0 + (it + 1) * 256, rb, rd, 1, it + 3 < 32);
    do_tile(tl0 + (it + 2) * 256, rc, ra, 0, it + 4 < 32);
    do_tile(tl0 + (it + 3) * 256, rd, rb, 1, it + 5 < 32);
  }
}

// ---------------- k_scan: in-chunk recurrence (CHUNK=32), 16-wave WGs ----------------
// A fragments self-split from f32 eW (A_t[n][k] = eW[n][k], contiguous rows).
__global__ __launch_bounds__(1024) void k_scan(const int pass,
                                               const float* __restrict__ eW,
                                               float* __restrict__ xu,  // d_out: u in (shifted), x out
                                               const float* __restrict__ Y,
                                               float* __restrict__ S) {
  const int tid = threadIdx.x;
  const int w = tid >> 6, l = tid & 63, l15 = l & 15, quad = l >> 4;
  const int ns = w * 16;  // 16 cols per wave
  const int c = blockIdx.x >> 2;
  const int rg = blockIdx.x & 3;
  __shared__ __align__(16) uint16_t sh[2][4096];
  __shared__ __align__(16) uint16_t sl[2][4096];

  const int t0 = c * CHUNK;
  const int nsteps = (t0 + CHUNK <= TLEN - 1) ? CHUNK : (TLEN - 1 - t0);

  float u0[4], u1[4], u2[4], u3[4], fin[4];
#pragma unroll
  for (int j = 0; j < 4; ++j) { u0[j] = 0.f; u1[j] = 0.f; u2[j] = 0.f; u3[j] = 0.f; fin[j] = 0.f; }

  auto issue_u = [&](int i, float (&dst)[4]) {
    if (i > nsteps) return;
#pragma unroll
    for (int r = 0; r < 4; ++r) {
      int b = rg * 16 + quad * 4 + r;
      dst[r] = xu[((size_t)b * TLEN + t0 + i) * DDIM + ns + l15];
    }
  };
  // fire the first 4 steps' u loads before anything else
  issue_u(1, u0);
  issue_u(2, u1);
  issue_u(3, u2);
  issue_u(4, u3);

  // A fragments: per-wave 16-col slice, split from f32 eW, pinned
  short8 fAh[8], fAl[8];
#pragma unroll
  for (int ks = 0; ks < 8; ++ks) {
    const float* ap = eW + (size_t)(ns + l15) * 256 + ks * 32 + quad * 8;
    f32x4 f0 = *reinterpret_cast<const f32x4*>(ap);
    f32x4 f1 = *reinterpret_cast<const f32x4*>(ap + 4);
    float fv[8] = {f0[0], f0[1], f0[2], f0[3], f1[0], f1[1], f1[2], f1[3]};
    split8(fv, fAh[ks], fAl[ks]);
    PIN8(fAh[ks]);
    PIN8(fAl[ks]);
  }

  // init state (buf 0)
  for (int i = tid; i < 4096; i += 1024) {
    int row = i >> 8, k = i & 255;
    float v;
    if (pass == 1)
      v = 0.0f;
    else {
      v = Y[((size_t)c * 64 + rg * 16 + row) * DDIM + k];
      if (c == 0) xu[((size_t)(rg * 16 + row) * TLEN) * DDIM + k] = v;  // x[:,0,:] = x0
    }
    uint16_t hb = f2bf(v);
    uint16_t lb = f2bf(v - bf2f(hb));
    uint32_t byte = ((uint32_t)(row * 512 + k * 2)) ^ swz(row);
    *(uint16_t*)((char*)sh[0] + byte) = hb;
    *(uint16_t*)((char*)sl[0] + byte) = lb;
  }
  wg_barrier();  // no vmcnt drain: u prefetches stay in flight

  int p = 0;
  auto step = [&](int i, float (&ucur)[4]) {
    f32x4 acc = {0.f, 0.f, 0.f, 0.f};
    __builtin_amdgcn_s_setprio(1);
#pragma unroll
    for (int ks = 0; ks < 8; ++ks) {
      uint32_t byte = ((uint32_t)(l15 * 512 + ks * 64 + quad * 16)) ^ swz(l15);
      short8 xh = *reinterpret_cast<const short8*>((const char*)sh[p] + byte);
      short8 xl = *reinterpret_cast<const short8*>((const char*)sl[p] + byte);
      acc = MFMA16(xh, fAh[ks], acc);
      acc = MFMA16(xl, fAh[ks], acc);
      acc = MFMA16(xh, fAl[ks], acc);
    }
    __builtin_amdgcn_s_setprio(0);
#pragma unroll
    for (int r = 0; r < 4; ++r) fin[r] = acc[r] + ucur[r];
    issue_u(i + 4, ucur);  // refill this buffer for step i+4
    if (pass == 2) {
#pragma unroll
      for (int r = 0; r < 4; ++r) {
        int b = rg * 16 + quad * 4 + r;
        xu[((size_t)b * TLEN + t0 + i) * DDIM + ns + l15] = fin[r];
      }
    }
    if (i < nsteps) {
#pragma unroll
      for (int r = 0; r < 4; ++r) {
        int row = quad * 4 + r, col = ns + l15;
        float v = fin[r];
        uint16_t hb = f2bf(v);
        uint16_t lb = f2bf(v - bf2f(hb));
        uint32_t byte = ((uint32_t)(row * 512 + col * 2)) ^ swz(row);
        *(uint16_t*)((char*)sh[p ^ 1] + byte) = hb;
        *(uint16_t*)((char*)sl[p ^ 1] + byte) = lb;
      }
      wg_barrier();
      p ^= 1;
    }
  };

  int i = 1;
  for (; i + 3 <= nsteps; i += 4) {
    step(i, u0);
    step(i + 1, u1);
    step(i + 2, u2);
    step(i + 3, u3);
  }
  if (i <= nsteps) { step(i, u0); ++i; }
  if (i <= nsteps) { step(i, u1); ++i; }
  if (i <= nsteps) { step(i, u2); ++i; }

  if (pass == 1) {
#pragma unroll
    for (int r = 0; r < 4; ++r) {
      int row = quad * 4 + r, col = ns + l15;
      S[((size_t)c * 64 + rg * 16 + row) * DDIM + col] = fin[r];
    }
  }
}

// ---------------- k_mm256A: OUT = Abar @ Abar from raw eW (stage 1) ----------------
// Abar = eW^T. A-frag: Abar[row][k] = eW[k][row] (strided); B-frag: split of
// contiguous eW rows (plane[n][k] = eW[n][k] = Abar[k][n]).
__global__ __launch_bounds__(512) void k_mm256A(const float* __restrict__ eW,
                                                float* __restrict__ Of,
                                                uint16_t* __restrict__ Oh,
                                                uint16_t* __restrict__ Ol) {
  const int mf = blockIdx.x;  // 0..15
  const int tid = threadIdx.x;
  const int w = tid >> 6, l = tid & 63, l15 = l & 15, quad = l >> 4;
  const int ns = w * 32;
  f32x4 acc[2];
  acc[0] = {0.f, 0.f, 0.f, 0.f};
  acc[1] = {0.f, 0.f, 0.f, 0.f};

#pragma unroll
  for (int ks = 0; ks < 8; ++ks) {
    float fv[8];
#pragma unroll
    for (int j = 0; j < 8; ++j)
      fv[j] = eW[(size_t)(ks * 32 + quad * 8 + j) * 256 + mf * 16 + l15];
    short8 ah, al8;
    split8(fv, ah, al8);
#pragma unroll
    for (int nf = 0; nf < 2; ++nf) {
      const float* bp = eW + (size_t)(ns + nf * 16 + l15) * 256 + ks * 32 + quad * 8;
      f32x4 b0 = *reinterpret_cast<const f32x4*>(bp);
      f32x4 b1 = *reinterpret_cast<const f32x4*>(bp + 4);
      float bv[8] = {b0[0], b0[1], b0[2], b0[3], b1[0], b1[1], b1[2], b1[3]};
      short8 bhf, blf;
      split8(bv, bhf, blf);
      acc[nf] = MFMA16(ah, bhf, acc[nf]);
      acc[nf] = MFMA16(al8, bhf, acc[nf]);
      acc[nf] = MFMA16(ah, blf, acc[nf]);
    }
  }
#pragma unroll
  for (int nf = 0; nf < 2; ++nf)
#pragma unroll
    for (int r = 0; r < 4; ++r) {
      int row = mf * 16 + quad * 4 + r;
      int col = ns + nf * 16 + l15;
      float v = acc[nf][r];
      Of[(size_t)row * 256 + col] = v;
      uint16_t hb = f2bf(v);
      Oh[(size_t)col * 256 + row] = hb;
      Ol[(size_t)col * 256 + row] = f2bf(v - bf2f(hb));
    }
}

// ---------------- k_mm256: OUT = Af @ B, 16 WGs (stages 2+) ----------------
__global__ __launch_bounds__(512) void k_mm256(const float* __restrict__ Af,
                                               const uint16_t* __restrict__ Bh,
                                               const uint16_t* __restrict__ Bl,
                                               float* __restrict__ Of,
                                               uint16_t* __restrict__ Oh,
                                               uint16_t* __restrict__ Ol) {
  const int mf = blockIdx.x;  // 0..15
  const int tid = threadIdx.x;
  const int w = tid >> 6, l = tid & 63, l15 = l & 15, quad = l >> 4;
  const int ns = w * 32;
  f32x4 acc[2];
  acc[0] = {0.f, 0.f, 0.f, 0.f};
  acc[1] = {0.f, 0.f, 0.f, 0.f};

#pragma unroll
  for (int ks = 0; ks < 8; ++ks) {
    const float* ap = Af + (size_t)(mf * 16 + l15) * 256 + ks * 32 + quad * 8;
    f32x4 f0 = *reinterpret_cast<const f32x4*>(ap);
    f32x4 f1 = *reinterpret_cast<const f32x4*>(ap + 4);
    float fv[8] = {f0[0], f0[1], f0[2], f0[3], f1[0], f1[1], f1[2], f1[3]};
    short8 ah, al8;
    split8(fv, ah, al8);
#pragma unroll
    for (int nf = 0; nf < 2; ++nf) {
      const int off = (ns + nf * 16 + l15) * 256 + ks * 32 + quad * 8;
      short8 bhf = *reinterpret_cast<const short8*>(Bh + off);
      short8 blf = *reinterpret_cast<const short8*>(Bl + off);
      acc[nf] = MFMA16(ah, bhf, acc[nf]);
      acc[nf] = MFMA16(al8, bhf, acc[nf]);
      acc[nf] = MFMA16(ah, blf, acc[nf]);
    }
  }
#pragma unroll
  for (int nf = 0; nf < 2; ++nf)
#pragma unroll
    for (int r = 0; r < 4; ++r) {
      int row = mf * 16 + quad * 4 + r;
      int col = ns + nf * 16 + l15;
      float v = acc[nf][r];
      Of[(size_t)row * 256 + col] = v;
      uint16_t hb = f2bf(v);
      Oh[(size_t)col * 256 + row] = hb;
      Ol[(size_t)col * 256 + row] = f2bf(v - bf2f(hb));
    }
}

// ---------------- k_bnd: boundary states, J=2 ----------------
// Y_c = T_c + T_{c-1}@M1 + T_{c-2}@M2; T_0=x0, T_k=S_{k-1}; M1=A^32, M2=A^64.
__global__ __launch_bounds__(512) void k_bnd(const float* __restrict__ x0,
                                             const float* __restrict__ S,
                                             const uint16_t* __restrict__ M1h, const uint16_t* __restrict__ M1l,
                                             const uint16_t* __restrict__ M2h, const uint16_t* __restrict__ M2l,
                                             float* __restrict__ Y) {
  const int c = blockIdx.x;
  const int tid = threadIdx.x;
  const int w = tid >> 6, l = tid & 63, l15 = l & 15, quad = l >> 4;
  const int ns = w * 32;
  f32x4 acc[4][2];
  const float* Tc = (c == 0) ? x0 : (S + (size_t)(c - 1) * 64 * 256);
#pragma unroll
  for (int mf = 0; mf < 4; ++mf)
#pragma unroll
    for (int nf = 0; nf < 2; ++nf)
#pragma unroll
      for (int r = 0; r < 4; ++r)
        acc[mf][nf][r] = Tc[(size_t)(mf * 16 + quad * 4 + r) * 256 + ns + nf * 16 + l15];

  for (int j = 1; j <= 2; ++j) {
    int k = c - j;
    if (k < 0) break;
    const float* Tp = (k == 0) ? x0 : (S + (size_t)(k - 1) * 64 * 256);
    const uint16_t* Bh = (j == 1) ? M1h : M2h;
    const uint16_t* Bl = (j == 1) ? M1l : M2l;
#pragma unroll
    for (int mf = 0; mf < 4; ++mf) {
#pragma unroll
      for (int ks = 0; ks < 8; ++ks) {
        const float* ap = Tp + (size_t)(mf * 16 + l15) * 256 + ks * 32 + quad * 8;
        f32x4 f0 = *reinterpret_cast<const f32x4*>(ap);
        f32x4 f1 = *reinterpret_cast<const f32x4*>(ap + 4);
        float fv[8] = {f0[0], f0[1], f0[2], f0[3], f1[0], f1[1], f1[2], f1[3]};
        short8 ah, al8;
        split8(fv, ah, al8);
#pragma unroll
        for (int nf = 0; nf < 2; ++nf) {
          const int off = (ns + nf * 16 + l15) * 256 + ks * 32 + quad * 8;
          short8 bhf = *reinterpret_cast<const short8*>(Bh + off);
          short8 blf = *reinterpret_cast<const short8*>(Bl + off);
          acc[mf][nf] = MFMA16(ah, bhf, acc[mf][nf]);
          acc[mf][nf] = MFMA16(al8, bhf, acc[mf][nf]);
          acc[mf][nf] = MFMA16(ah, blf, acc[mf][nf]);
        }
      }
    }
  }
#pragma unroll
  for (int mf = 0; mf < 4; ++mf)
#pragma unroll
    for (int nf = 0; nf < 2; ++nf)
#pragma unroll
      for (int r = 0; r < 4; ++r)
        Y[(size_t)c * 64 * 256 + (size_t)(mf * 16 + quad * 4 + r) * 256 + ns + nf * 16 + l15] =
            acc[mf][nf][r];
}

// ---------------- launch ----------------
extern "C" void kernel_launch(void* const* d_in, const int* in_sizes, int n_in,
                              void* d_out, int out_size, void* d_ws, size_t ws_size,
                              hipStream_t stream) {
  (void)in_sizes; (void)n_in; (void)out_size; (void)ws_size;
  const float* x0 = (const float*)d_in[0];
  const float* I  = (const float*)d_in[1];
  const float* eW = (const float*)d_in[2];
  const float* Wi = (const float*)d_in[3];
  float* out = (float*)d_out;
  char* ws = (char*)d_ws;

  float*    M1f = (float*)(ws + WS_M1F);
  uint16_t* M1h = (uint16_t*)(ws + WS_M1_HI);
  uint16_t* M1l = (uint16_t*)(ws + WS_M1_LO);
  float*    M2f = (float*)(ws + WS_M2F);
  uint16_t* M2h = (uint16_t*)(ws + WS_M2_HI);
  uint16_t* M2l = (uint16_t*)(ws + WS_M2_LO);
  float*    M3f = (float*)(ws + WS_M3F);
  uint16_t* M3h = (uint16_t*)(ws + WS_M3_HI);
  uint16_t* M3l = (uint16_t*)(ws + WS_M3_LO);
  float*    S   = (float*)(ws + WS_S);
  float*    Y   = (float*)(ws + WS_Y);

  k_u<<<256, 1024, 0, stream>>>(I, Wi, out);
  // M-power chain (Abar=eW^T): A^2 -> A^4 -> A^8 -> A^16 -> A^32(M1) -> A^64(M2)
  k_mm256A<<<16, 512, 0, stream>>>(eW, M3f, M3h, M3l);            // A^2
  k_mm256<<<16, 512, 0, stream>>>(M3f, M3h, M3l, M2f, M2h, M2l);  // A^4
  k_mm256<<<16, 512, 0, stream>>>(M2f, M2h, M2l, M3f, M3h, M3l);  // A^8
  k_mm256<<<16, 512, 0, stream>>>(M3f, M3h, M3l, M2f, M2h, M2l);  // A^16
  k_mm256<<<16, 512, 0, stream>>>(M2f, M2h, M2l, M1f, M1h, M1l);  // A^32 -> M1
  k_mm256<<<16, 512, 0, stream>>>(M1f, M1h, M1l, M2f, M2h, M2l);  // A^64 -> M2
  k_scan<<<256, 1024, 0, stream>>>(1, eW, out, Y, S);
  k_bnd<<<64, 512, 0, stream>>>(x0, S, M1h, M1l, M2h, M2l, Y);
  k_scan<<<256, 1024, 0, stream>>>(2, eW, out, Y, S);
}

// Round 10
// 282.416 us; speedup vs baseline: 1.3497x; 1.0530x over previous
//
#include <hip/hip_runtime.h>
#include <stdint.h>
#include <stddef.h>

// ISNNet: x[:,0]=x0; x[:,t] = x[:,t-1] @ eW.T + I[:,t-1] @ W_inv_eW.T
// B=64, T=2048, D=256.  3-term compensated bf16 MFMA throughout.
// Round 10: k_u -> 32x32x16 MFMA (4x A-fragment reuse, halves LDS traffic &
// MFMA instr count); k_bnd fused into scan pass-2 init (one fewer dispatch,
// no Y round-trip). 9 dispatches total.

#define BATCH 64
#define TLEN 2048
#define DDIM 256
#define CHUNK 32
#define NCHUNK 64

typedef __attribute__((ext_vector_type(8))) short short8;
typedef __attribute__((ext_vector_type(4))) float f32x4;
typedef __attribute__((ext_vector_type(16))) float f32x16;

#define MFMA16(a, b, c) __builtin_amdgcn_mfma_f32_16x16x32_bf16((a), (b), (c), 0, 0, 0)
#define MFMA32(a, b, c) __builtin_amdgcn_mfma_f32_32x32x16_bf16((a), (b), (c), 0, 0, 0)
#define PIN8(x) asm volatile("" : "+v"(x))

__device__ __forceinline__ uint16_t f2bf(float f) {
  union { float f; uint32_t u; } v; v.f = f;
  return (uint16_t)((v.u + 0x7fffu + ((v.u >> 16) & 1u)) >> 16);  // RNE
}
__device__ __forceinline__ float bf2f(uint16_t h) {
  union { uint32_t u; float f; } v; v.u = ((uint32_t)h) << 16;
  return v.f;
}

__device__ __forceinline__ void split8(const float* fv, short8& hi, short8& lo) {
#pragma unroll
  for (int j = 0; j < 8; ++j) {
    uint16_t hb = f2bf(fv[j]);
    hi[j] = (short)hb;
    lo[j] = (short)f2bf(fv[j] - bf2f(hb));
  }
}

// 16-row swizzle (scan state tiles)
__device__ __forceinline__ uint32_t swz(int row) {
  return ((uint32_t)((row & 7) << 4)) ^ ((uint32_t)(((row >> 3) & 1) << 7));
}
// 32-row swizzle (k_u I-tiles)
__device__ __forceinline__ uint32_t swz32(int row) {
  return ((uint32_t)((row & 7) << 4)) ^ ((uint32_t)(((row >> 3) & 3) << 7));
}

// raw barrier: waits LDS ops but NOT outstanding global loads
__device__ __forceinline__ void wg_barrier() {
  __builtin_amdgcn_sched_barrier(0);
  asm volatile("s_waitcnt lgkmcnt(0)" ::: "memory");
  __builtin_amdgcn_s_barrier();
  asm volatile("" ::: "memory");
  __builtin_amdgcn_sched_barrier(0);
}

// ---------------- workspace layout (bytes) ----------------
#define WS_M1F    (0)            // f32 [256][256]
#define WS_M1_HI  (256 * 1024)
#define WS_M1_LO  (384 * 1024)
#define WS_M2F    (512 * 1024)
#define WS_M2_HI  (768 * 1024)
#define WS_M2_LO  (896 * 1024)
#define WS_M3F    (1024 * 1024)
#define WS_M3_HI  (1280 * 1024)
#define WS_M3_LO  (1408 * 1024)
#define WS_S      (2560 * 1024)  // f32 [64][64][256] = 4MB

// ---------------- k_u: u = I @ Wi^T -> d_out at time t+1 (32x32x16 MFMA) ----
// 8 waves x (32 rows x 32 cols); 256 WGs x 16 tiles of 32 t-rows; LDS dbuf.
__global__ __launch_bounds__(512, 1) void k_u(const float* __restrict__ I,
                                              const float* __restrict__ Wi,
                                              float* __restrict__ out) {
  const int tid = threadIdx.x;
  const int w = tid >> 6, l = tid & 63, l31 = l & 31, half = l >> 5;
  const int ns = w * 32;  // 32 cols per wave
  __shared__ __align__(16) uint16_t sIh[2][8192];  // 32 x 256 bf16, swizzled
  __shared__ __align__(16) uint16_t sIl[2][8192];

  // Wb fragments: col = ns+l31, k = ks*16 + half*8 .. +8  (128 regs, pinned)
  short8 bh[16], bl[16];
#pragma unroll
  for (int ks = 0; ks < 16; ++ks) {
    const float* wp = Wi + (size_t)(ns + l31) * 256 + ks * 16 + half * 8;
    f32x4 f0 = *reinterpret_cast<const f32x4*>(wp);
    f32x4 f1 = *reinterpret_cast<const f32x4*>(wp + 4);
    float fv[8] = {f0[0], f0[1], f0[2], f0[3], f1[0], f1[1], f1[2], f1[3]};
    split8(fv, bh[ks], bl[ks]);
    PIN8(bh[ks]);
    PIN8(bl[ks]);
  }

  const int srow = tid >> 4;        // 0..31 (staging row)
  const int sc0 = (tid & 15) * 16;  // 0..240 (staging col base, 16 f32)
  const uint32_t wb0 = ((uint32_t)(srow * 512 + sc0 * 2)) ^ swz32(srow);
  const uint32_t wb1 = ((uint32_t)(srow * 512 + sc0 * 2 + 16)) ^ swz32(srow);

  f32x4 ra[4], rb[4];
  auto loadI = [&](int tl, f32x4 (&dst)[4]) {
    const int b = tl >> 6, tt = tl & 63;
    const float* src = I + ((size_t)b * TLEN + tt * 32 + srow) * DDIM + sc0;
#pragma unroll
    for (int j = 0; j < 4; ++j)
      dst[j] = *reinterpret_cast<const f32x4*>(src + j * 4);
  };

  auto do_tile = [&](int tl, f32x4 (&cur)[4], int q, bool pre) {
    short8 hi[2], lo[2];
#pragma unroll
    for (int h2 = 0; h2 < 2; ++h2) {
      float fv[8] = {cur[h2 * 2][0], cur[h2 * 2][1], cur[h2 * 2][2], cur[h2 * 2][3],
                     cur[h2 * 2 + 1][0], cur[h2 * 2 + 1][1], cur[h2 * 2 + 1][2], cur[h2 * 2 + 1][3]};
      split8(fv, hi[h2], lo[h2]);
    }
    if (pre) loadI(tl + 512, cur);   // reload same buffer for tile tl+2
    *reinterpret_cast<short8*>(reinterpret_cast<char*>(sIh[q]) + wb0) = hi[0];
    *reinterpret_cast<short8*>(reinterpret_cast<char*>(sIh[q]) + wb1) = hi[1];
    *reinterpret_cast<short8*>(reinterpret_cast<char*>(sIl[q]) + wb0) = lo[0];
    *reinterpret_cast<short8*>(reinterpret_cast<char*>(sIl[q]) + wb1) = lo[1];
    wg_barrier();                    // writes of buf q visible; buf q^1 free
    const int b = tl >> 6, tt = tl & 63;
    f32x16 acc = {0.f};
#pragma unroll
    for (int j = 0; j < 16; ++j) acc[j] = 0.f;
    __builtin_amdgcn_s_setprio(1);
#pragma unroll
    for (int ks = 0; ks < 16; ++ks) {
      uint32_t rbyte = ((uint32_t)(l31 * 512 + ks * 32 + half * 16)) ^ swz32(l31);
      short8 ih = *reinterpret_cast<const short8*>((const char*)sIh[q] + rbyte);
      short8 il = *reinterpret_cast<const short8*>((const char*)sIl[q] + rbyte);
      acc = MFMA32(ih, bh[ks], acc);
      acc = MFMA32(il, bh[ks], acc);
      acc = MFMA32(ih, bl[ks], acc);
    }
    __builtin_amdgcn_s_setprio(0);
#pragma unroll
    for (int r = 0; r < 16; ++r) {
      int row = (r & 3) + 8 * (r >> 2) + 4 * half;
      int trow = tt * 32 + row;
      if (trow <= TLEN - 2) {  // u_t lives at location t+1; t <= 2046
        out[((size_t)b * TLEN + trow + 1) * DDIM + ns + l31] = acc[r];
      }
    }
  };

  const int tl0 = blockIdx.x;  // 16 tiles: tl0 + k*256 (4096 tiles of 32 rows)
  loadI(tl0, ra);
  loadI(tl0 + 256, rb);
#pragma unroll 1
  for (int it = 0; it < 16; it += 2) {
    do_tile(tl0 + it * 256, ra, 0, it + 2 < 16);
    do_tile(tl0 + (it + 1) * 256, rb, 1, it + 3 < 16);
  }
}

// ---------------- k_scan: in-chunk recurrence (CHUNK=32), 16-wave WGs -------
// pass 2 init computes Y_c = T_c + T_{c-1}@M1 + T_{c-2}@M2 inline (fused bnd).
__global__ __launch_bounds__(1024) void k_scan(const int pass,
                                               const float* __restrict__ eW,
                                               float* __restrict__ xu,  // d_out: u in (shifted), x out
                                               const float* __restrict__ x0,
                                               float* __restrict__ S,
                                               const uint16_t* __restrict__ M1h,
                                               const uint16_t* __restrict__ M1l,
                                               const uint16_t* __restrict__ M2h,
                                               const uint16_t* __restrict__ M2l) {
  const int tid = threadIdx.x;
  const int w = tid >> 6, l = tid & 63, l15 = l & 15, quad = l >> 4;
  const int ns = w * 16;  // 16 cols per wave
  const int c = blockIdx.x >> 2;
  const int rg = blockIdx.x & 3;
  __shared__ __align__(16) uint16_t sh[2][4096];
  __shared__ __align__(16) uint16_t sl[2][4096];

  const int t0 = c * CHUNK;
  const int nsteps = (t0 + CHUNK <= TLEN - 1) ? CHUNK : (TLEN - 1 - t0);

  float u0[4], u1[4], u2[4], u3[4], fin[4];
#pragma unroll
  for (int j = 0; j < 4; ++j) { u0[j] = 0.f; u1[j] = 0.f; u2[j] = 0.f; u3[j] = 0.f; fin[j] = 0.f; }

  auto issue_u = [&](int i, float (&dst)[4]) {
    if (i > nsteps) return;
#pragma unroll
    for (int r = 0; r < 4; ++r) {
      int b = rg * 16 + quad * 4 + r;
      dst[r] = xu[((size_t)b * TLEN + t0 + i) * DDIM + ns + l15];
    }
  };
  // fire the first 4 steps' u loads before anything else
  issue_u(1, u0);
  issue_u(2, u1);
  issue_u(3, u2);
  issue_u(4, u3);

  // A fragments: per-wave 16-col slice, split from f32 eW, pinned
  short8 fAh[8], fAl[8];
#pragma unroll
  for (int ks = 0; ks < 8; ++ks) {
    const float* ap = eW + (size_t)(ns + l15) * 256 + ks * 32 + quad * 8;
    f32x4 f0 = *reinterpret_cast<const f32x4*>(ap);
    f32x4 f1 = *reinterpret_cast<const f32x4*>(ap + 4);
    float fv[8] = {f0[0], f0[1], f0[2], f0[3], f1[0], f1[1], f1[2], f1[3]};
    split8(fv, fAh[ks], fAl[ks]);
    PIN8(fAh[ks]);
    PIN8(fAl[ks]);
  }

  // init state (buf 0)
  if (pass == 1) {
    for (int i = tid; i < 4096; i += 1024) {
      int row = i >> 8, k = i & 255;
      uint32_t byte = ((uint32_t)(row * 512 + k * 2)) ^ swz(row);
      *(uint16_t*)((char*)sh[0] + byte) = 0;
      *(uint16_t*)((char*)sl[0] + byte) = 0;
    }
  } else {
    // fused k_bnd: Y = T_c + T_{c-1}@M1 + T_{c-2}@M2 for this WG's rows/cols
    f32x4 yacc;
    {
      const float* Tc = (c == 0) ? x0 : (S + (size_t)(c - 1) * 64 * 256);
#pragma unroll
      for (int r = 0; r < 4; ++r)
        yacc[r] = Tc[(size_t)(rg * 16 + quad * 4 + r) * 256 + ns + l15];
    }
#pragma unroll 1
    for (int j = 1; j <= 2; ++j) {
      int k = c - j;
      if (k < 0) break;
      const float* Tp = (k == 0) ? x0 : (S + (size_t)(k - 1) * 64 * 256);
      const uint16_t* Bh = (j == 1) ? M1h : M2h;
      const uint16_t* Bl = (j == 1) ? M1l : M2l;
#pragma unroll
      for (int ks = 0; ks < 8; ++ks) {
        const float* ap = Tp + (size_t)(rg * 16 + l15) * 256 + ks * 32 + quad * 8;
        f32x4 f0 = *reinterpret_cast<const f32x4*>(ap);
        f32x4 f1 = *reinterpret_cast<const f32x4*>(ap + 4);
        float fv[8] = {f0[0], f0[1], f0[2], f0[3], f1[0], f1[1], f1[2], f1[3]};
        short8 ah, al8;
        split8(fv, ah, al8);
        const int off = (ns + l15) * 256 + ks * 32 + quad * 8;
        short8 bhf = *reinterpret_cast<const short8*>(Bh + off);
        short8 blf = *reinterpret_cast<const short8*>(Bl + off);
        yacc = MFMA16(ah, bhf, yacc);
        yacc = MFMA16(al8, bhf, yacc);
        yacc = MFMA16(ah, blf, yacc);
      }
    }
#pragma unroll
    for (int r = 0; r < 4; ++r) {
      int row = quad * 4 + r, col = ns + l15;
      float v = yacc[r];
      if (c == 0) xu[((size_t)(rg * 16 + row) * TLEN) * DDIM + col] = v;  // x[:,0,:]
      uint16_t hb = f2bf(v);
      uint16_t lb = f2bf(v - bf2f(hb));
      uint32_t byte = ((uint32_t)(row * 512 + col * 2)) ^ swz(row);
      *(uint16_t*)((char*)sh[0] + byte) = hb;
      *(uint16_t*)((char*)sl[0] + byte) = lb;
    }
  }
  wg_barrier();  // no vmcnt drain: u prefetches stay in flight

  int p = 0;
  auto step = [&](int i, float (&ucur)[4]) {
    f32x4 acc = {0.f, 0.f, 0.f, 0.f};
    __builtin_amdgcn_s_setprio(1);
#pragma unroll
    for (int ks = 0; ks < 8; ++ks) {
      uint32_t byte = ((uint32_t)(l15 * 512 + ks * 64 + quad * 16)) ^ swz(l15);
      short8 xh = *reinterpret_cast<const short8*>((const char*)sh[p] + byte);
      short8 xl = *reinterpret_cast<const short8*>((const char*)sl[p] + byte);
      acc = MFMA16(xh, fAh[ks], acc);
      acc = MFMA16(xl, fAh[ks], acc);
      acc = MFMA16(xh, fAl[ks], acc);
    }
    __builtin_amdgcn_s_setprio(0);
#pragma unroll
    for (int r = 0; r < 4; ++r) fin[r] = acc[r] + ucur[r];
    issue_u(i + 4, ucur);  // refill this buffer for step i+4
    if (pass == 2) {
#pragma unroll
      for (int r = 0; r < 4; ++r) {
        int b = rg * 16 + quad * 4 + r;
        xu[((size_t)b * TLEN + t0 + i) * DDIM + ns + l15] = fin[r];
      }
    }
    if (i < nsteps) {
#pragma unroll
      for (int r = 0; r < 4; ++r) {
        int row = quad * 4 + r, col = ns + l15;
        float v = fin[r];
        uint16_t hb = f2bf(v);
        uint16_t lb = f2bf(v - bf2f(hb));
        uint32_t byte = ((uint32_t)(row * 512 + col * 2)) ^ swz(row);
        *(uint16_t*)((char*)sh[p ^ 1] + byte) = hb;
        *(uint16_t*)((char*)sl[p ^ 1] + byte) = lb;
      }
      wg_barrier();
      p ^= 1;
    }
  };

  int i = 1;
  for (; i + 3 <= nsteps; i += 4) {
    step(i, u0);
    step(i + 1, u1);
    step(i + 2, u2);
    step(i + 3, u3);
  }
  if (i <= nsteps) { step(i, u0); ++i; }
  if (i <= nsteps) { step(i, u1); ++i; }
  if (i <= nsteps) { step(i, u2); ++i; }

  if (pass == 1) {
#pragma unroll
    for (int r = 0; r < 4; ++r) {
      int row = quad * 4 + r, col = ns + l15;
      S[((size_t)c * 64 + rg * 16 + row) * DDIM + col] = fin[r];
    }
  }
}

// ---------------- k_mm256A: OUT = Abar @ Abar from raw eW (stage 1) ----------
__global__ __launch_bounds__(512) void k_mm256A(const float* __restrict__ eW,
                                                float* __restrict__ Of,
                                                uint16_t* __restrict__ Oh,
                                                uint16_t* __restrict__ Ol) {
  const int mf = blockIdx.x;  // 0..15
  const int tid = threadIdx.x;
  const int w = tid >> 6, l = tid & 63, l15 = l & 15, quad = l >> 4;
  const int ns = w * 32;
  f32x4 acc[2];
  acc[0] = {0.f, 0.f, 0.f, 0.f};
  acc[1] = {0.f, 0.f, 0.f, 0.f};

#pragma unroll
  for (int ks = 0; ks < 8; ++ks) {
    float fv[8];
#pragma unroll
    for (int j = 0; j < 8; ++j)
      fv[j] = eW[(size_t)(ks * 32 + quad * 8 + j) * 256 + mf * 16 + l15];
    short8 ah, al8;
    split8(fv, ah, al8);
#pragma unroll
    for (int nf = 0; nf < 2; ++nf) {
      const float* bp = eW + (size_t)(ns + nf * 16 + l15) * 256 + ks * 32 + quad * 8;
      f32x4 b0 = *reinterpret_cast<const f32x4*>(bp);
      f32x4 b1 = *reinterpret_cast<const f32x4*>(bp + 4);
      float bv[8] = {b0[0], b0[1], b0[2], b0[3], b1[0], b1[1], b1[2], b1[3]};
      short8 bhf, blf;
      split8(bv, bhf, blf);
      acc[nf] = MFMA16(ah, bhf, acc[nf]);
      acc[nf] = MFMA16(al8, bhf, acc[nf]);
      acc[nf] = MFMA16(ah, blf, acc[nf]);
    }
  }
#pragma unroll
  for (int nf = 0; nf < 2; ++nf)
#pragma unroll
    for (int r = 0; r < 4; ++r) {
      int row = mf * 16 + quad * 4 + r;
      int col = ns + nf * 16 + l15;
      float v = acc[nf][r];
      Of[(size_t)row * 256 + col] = v;
      uint16_t hb = f2bf(v);
      Oh[(size_t)col * 256 + row] = hb;
      Ol[(size_t)col * 256 + row] = f2bf(v - bf2f(hb));
    }
}

// ---------------- k_mm256: OUT = Af @ B, 16 WGs (stages 2+) ----------------
__global__ __launch_bounds__(512) void k_mm256(const float* __restrict__ Af,
                                               const uint16_t* __restrict__ Bh,
                                               const uint16_t* __restrict__ Bl,
                                               float* __restrict__ Of,
                                               uint16_t* __restrict__ Oh,
                                               uint16_t* __restrict__ Ol) {
  const int mf = blockIdx.x;  // 0..15
  const int tid = threadIdx.x;
  const int w = tid >> 6, l = tid & 63, l15 = l & 15, quad = l >> 4;
  const int ns = w * 32;
  f32x4 acc[2];
  acc[0] = {0.f, 0.f, 0.f, 0.f};
  acc[1] = {0.f, 0.f, 0.f, 0.f};

#pragma unroll
  for (int ks = 0; ks < 8; ++ks) {
    const float* ap = Af + (size_t)(mf * 16 + l15) * 256 + ks * 32 + quad * 8;
    f32x4 f0 = *reinterpret_cast<const f32x4*>(ap);
    f32x4 f1 = *reinterpret_cast<const f32x4*>(ap + 4);
    float fv[8] = {f0[0], f0[1], f0[2], f0[3], f1[0], f1[1], f1[2], f1[3]};
    short8 ah, al8;
    split8(fv, ah, al8);
#pragma unroll
    for (int nf = 0; nf < 2; ++nf) {
      const int off = (ns + nf * 16 + l15) * 256 + ks * 32 + quad * 8;
      short8 bhf = *reinterpret_cast<const short8*>(Bh + off);
      short8 blf = *reinterpret_cast<const short8*>(Bl + off);
      acc[nf] = MFMA16(ah, bhf, acc[nf]);
      acc[nf] = MFMA16(al8, bhf, acc[nf]);
      acc[nf] = MFMA16(ah, blf, acc[nf]);
    }
  }
#pragma unroll
  for (int nf = 0; nf < 2; ++nf)
#pragma unroll
    for (int r = 0; r < 4; ++r) {
      int row = mf * 16 + quad * 4 + r;
      int col = ns + nf * 16 + l15;
      float v = acc[nf][r];
      Of[(size_t)row * 256 + col] = v;
      uint16_t hb = f2bf(v);
      Oh[(size_t)col * 256 + row] = hb;
      Ol[(size_t)col * 256 + row] = f2bf(v - bf2f(hb));
    }
}

// ---------------- launch ----------------
extern "C" void kernel_launch(void* const* d_in, const int* in_sizes, int n_in,
                              void* d_out, int out_size, void* d_ws, size_t ws_size,
                              hipStream_t stream) {
  (void)in_sizes; (void)n_in; (void)out_size; (void)ws_size;
  const float* x0 = (const float*)d_in[0];
  const float* I  = (const float*)d_in[1];
  const float* eW = (const float*)d_in[2];
  const float* Wi = (const float*)d_in[3];
  float* out = (float*)d_out;
  char* ws = (char*)d_ws;

  float*    M1f = (float*)(ws + WS_M1F);
  uint16_t* M1h = (uint16_t*)(ws + WS_M1_HI);
  uint16_t* M1l = (uint16_t*)(ws + WS_M1_LO);
  float*    M2f = (float*)(ws + WS_M2F);
  uint16_t* M2h = (uint16_t*)(ws + WS_M2_HI);
  uint16_t* M2l = (uint16_t*)(ws + WS_M2_LO);
  float*    M3f = (float*)(ws + WS_M3F);
  uint16_t* M3h = (uint16_t*)(ws + WS_M3_HI);
  uint16_t* M3l = (uint16_t*)(ws + WS_M3_LO);
  float*    S   = (float*)(ws + WS_S);

  k_u<<<256, 512, 0, stream>>>(I, Wi, out);
  // M-power chain (Abar=eW^T): A^2 -> A^4 -> A^8 -> A^16 -> A^32(M1) -> A^64(M2)
  k_mm256A<<<16, 512, 0, stream>>>(eW, M3f, M3h, M3l);            // A^2
  k_mm256<<<16, 512, 0, stream>>>(M3f, M3h, M3l, M2f, M2h, M2l);  // A^4
  k_mm256<<<16, 512, 0, stream>>>(M2f, M2h, M2l, M3f, M3h, M3l);  // A^8
  k_mm256<<<16, 512, 0, stream>>>(M3f, M3h, M3l, M2f, M2h, M2l);  // A^16
  k_mm256<<<16, 512, 0, stream>>>(M2f, M2h, M2l, M1f, M1h, M1l);  // A^32 -> M1
  k_mm256<<<16, 512, 0, stream>>>(M1f, M1h, M1l, M2f, M2h, M2l);  // A^64 -> M2
  k_scan<<<256, 1024, 0, stream>>>(1, eW, out, x0, S, M1h, M1l, M2h, M2l);
  k_scan<<<256, 1024, 0, stream>>>(2, eW, out, x0, S, M1h, M1l, M2h, M2l);
}